// Round 8
// baseline (210.874 us; speedup 1.0000x reference)
//
#include <hip/hip_runtime.h>
#include <math.h>

#define NN 20000     // nodes
#define NE 320000    // edges
#define NR 500       // relations
#define EMBD 256
#define D4 64
#define BQ 32        // batch
#define TOT (2 * NN)     // bins (in | out)
#define NPART 8          // CSR partitions (~XCDs)
#define TOT2 (NPART * TOT)
#define NB2 ((TOT2 + 1023) / 1024)   // 313 partition-scan blocks
#define NB3 ((TOT + 1023) / 1024)    // 40 bin-scan blocks
#define NBLK_BN 448  // buildBn data blocks

typedef __attribute__((ext_vector_type(8))) short bf16x8;
typedef __attribute__((ext_vector_type(4))) float f32x4;

__device__ __forceinline__ unsigned short f2bf(float x)
{
    unsigned int u = __float_as_uint(x);
    unsigned int r = (u + 0x7fffu + ((u >> 16) & 1u)) >> 16;   // RNE
    return (unsigned short)r;
}

// ---------------- weight pack + folded param kernel ----------------
__global__ void k_buildBn(const float* __restrict__ W_O1, const float* __restrict__ W_I1,
                          const float* __restrict__ W_S1, const float* __restrict__ Wr1,
                          const float* __restrict__ W_O2, const float* __restrict__ W_I2,
                          const float* __restrict__ W_S2,
                          unsigned short* __restrict__ Bn1, unsigned short* __restrict__ Bn2,
                          const float* __restrict__ bO1, const float* __restrict__ bI1,
                          const float* __restrict__ bS1,
                          const float* __restrict__ g1, const float* __restrict__ bb1,
                          const float* __restrict__ m1, const float* __restrict__ v1,
                          const float* __restrict__ bO2, const float* __restrict__ bI2,
                          const float* __restrict__ bS2,
                          const float* __restrict__ g2, const float* __restrict__ bb2,
                          const float* __restrict__ m2, const float* __restrict__ v2,
                          float* __restrict__ s1, float* __restrict__ t1,
                          float* __restrict__ s2, float* __restrict__ t2)
{
    int b = blockIdx.x;
    if (b >= NBLK_BN) {
        int i = (b - NBLK_BN) * 256 + threadIdx.x;   // [0,512)
        if (i < 64) {
            float rsg = g1[i] / sqrtf(v1[i] + 1e-5f);
            s1[i] = rsg * (1.f / 3.f);
            t1[i] = ((bO1[i] + bI1[i] + bS1[i]) * (1.f / 3.f) - m1[i]) * rsg + bb1[i];
        } else if (i < 320) {
            int n = i - 64;
            float rsg = g2[n] / sqrtf(v2[n] + 1e-5f);
            s2[n] = rsg * (1.f / 3.f);
            t2[n] = ((bO2[n] + bI2[n] + bS2[n]) * (1.f / 3.f) - m2[n]) * rsg + bb2[n];
        }
        return;
    }
    int id = b * 256 + threadIdx.x;
    if (id < 256 * 256) {
        int n = id >> 8, k = id & 255;
        float v;
        if (n < 64)       v = W_O1[n * 256 + k];
        else if (n < 128) v = W_I1[(n - 64) * 256 + k];
        else if (n < 192) v = W_S1[(n - 128) * 256 + k];
        else              v = Wr1[(n - 192) * 256 + k];
        Bn1[id] = f2bf(v);
    } else {
        int id2 = id - 256 * 256;
        if (id2 < 256 * 192) {
            int n = id2 / 192, k = id2 - n * 192;
            float v;
            if (k < 64)       v = W_O2[n * 64 + k];
            else if (k < 128) v = W_I2[n * 64 + (k - 64)];
            else              v = W_S2[n * 64 + (k - 128)];
            Bn2[id2] = f2bf(v);
        }
    }
}

// ---------------- CSR build (partition-major scatter, bin-major repack) ----------------
// cnt2[p*TOT + bin], bin = dst (in) or NN+src (out); partition p = blockIdx&7

__global__ void k_hist(const int* __restrict__ src, const int* __restrict__ dst,
                       int* __restrict__ cnt2)
{
    int i = blockIdx.x * 256 + threadIdx.x;
    int part = blockIdx.x & (NPART - 1);
    if (i < NE) {
        int base = part * TOT;
        atomicAdd(&cnt2[base + dst[i]], 1);
        atomicAdd(&cnt2[base + NN + src[i]], 1);
    }
}

// binTotal[bin] = sum over partitions
__global__ void k_sumbins(const int* __restrict__ cnt2, int* __restrict__ binTotal)
{
    int bin = blockIdx.x * 256 + threadIdx.x;
    if (bin < TOT) {
        int s = 0;
#pragma unroll
        for (int p = 0; p < NPART; ++p) s += cnt2[p * TOT + bin];
        binTotal[bin] = s;
    }
}

// phase A: per-block (1024 elems) sum -> bsum
__global__ __launch_bounds__(256) void k_scanA(const int* __restrict__ cnt,
                                               int* __restrict__ bsum, int len)
{
    __shared__ int lds[256];
    int t = threadIdx.x;
    int base = blockIdx.x * 1024 + t * 4;
    int s = 0;
    if (base + 3 < len) {
        int4 v = *(const int4*)(cnt + base);
        s = v.x + v.y + v.z + v.w;
    } else {
        for (int c = 0; c < 4; ++c) { int i = base + c; if (i < len) s += cnt[i]; }
    }
    lds[t] = s;
    __syncthreads();
    for (int d = 128; d > 0; d >>= 1) {
        if (t < d) lds[t] += lds[t + d];
        __syncthreads();
    }
    if (t == 0) bsum[blockIdx.x] = lds[0];
}

// phase B: one wave exclusive-scans nb block sums in place (chunked)
__global__ __launch_bounds__(64) void k_scanB(int* __restrict__ bsum, int nb)
{
    int t = threadIdx.x;
    int carry = 0;
    for (int c = 0; c < nb; c += 64) {
        int i = c + t;
        int v = (i < nb) ? bsum[i] : 0;
        int vin = v;
#pragma unroll
        for (int d = 1; d < 64; d <<= 1) {
            int u = __shfl_up(v, d, 64);
            if (t >= d) v += u;
        }
        if (i < nb) bsum[i] = (v - vin) + carry;
        carry += __shfl(v, 63, 64);
    }
}

// phase C: local exclusive scan + block offset -> off (and cur if wantCur)
__global__ __launch_bounds__(256) void k_scanC(const int* __restrict__ cnt,
                                               const int* __restrict__ bsum,
                                               int* __restrict__ off,
                                               int* __restrict__ cur,
                                               int len, int total, int wantCur)
{
    __shared__ int lds[256];
    int t = threadIdx.x;
    int base = blockIdx.x * 1024 + t * 4;
    int e0 = 0, e1 = 0, e2 = 0, e3 = 0;
    if (base + 3 < len) {
        int4 v = *(const int4*)(cnt + base);
        e0 = v.x; e1 = v.y; e2 = v.z; e3 = v.w;
    } else {
        if (base + 0 < len) e0 = cnt[base + 0];
        if (base + 1 < len) e1 = cnt[base + 1];
        if (base + 2 < len) e2 = cnt[base + 2];
        if (base + 3 < len) e3 = cnt[base + 3];
    }
    int s = e0 + e1 + e2 + e3;
    lds[t] = s;
    __syncthreads();
    for (int d = 1; d < 256; d <<= 1) {
        int u = (t >= d) ? lds[t - d] : 0;
        __syncthreads();
        lds[t] += u;
        __syncthreads();
    }
    int run = lds[t] - s + bsum[blockIdx.x];
    if (base + 3 < len) {
        int4 o = make_int4(run, run + e0, run + e0 + e1, run + e0 + e1 + e2);
        *(int4*)(off + base) = o;
        if (wantCur) *(int4*)(cur + base) = o;
    } else {
        int r = run;
        if (base + 0 < len) { off[base + 0] = r; if (wantCur) cur[base + 0] = r; r += e0; }
        if (base + 1 < len) { off[base + 1] = r; if (wantCur) cur[base + 1] = r; r += e1; }
        if (base + 2 < len) { off[base + 2] = r; if (wantCur) cur[base + 2] = r; r += e2; }
        if (base + 3 < len) { off[base + 3] = r; if (wantCur) cur[base + 3] = r; r += e3; }
    }
    if (blockIdx.x == 0 && t == 0) off[len] = total;
}

// scatter PACKED records (other | evid<<15) into partition-major R
__global__ void k_scatter(const int* __restrict__ src, const int* __restrict__ dst,
                          const int* __restrict__ evid,
                          int* __restrict__ cur, unsigned* __restrict__ R)
{
    int e = blockIdx.x * 256 + threadIdx.x;
    int part = blockIdx.x & (NPART - 1);
    if (e >= NE) return;
    int s = src[e], d = dst[e];
    unsigned rv = (unsigned)evid[e] << 15;
    int base = part * TOT;
    int p = atomicAdd(&cur[base + d], 1);
    R[p] = (unsigned)s | rv;
    int q = atomicAdd(&cur[base + NN + s], 1);
    R[q] = (unsigned)d | rv;
}

// repack partition-major R -> bin-major R2 (one thread per bin)
__global__ void k_repack(const int* __restrict__ offc2, const int* __restrict__ off_bin,
                         const unsigned* __restrict__ R, unsigned* __restrict__ R2)
{
    int bin = blockIdx.x * 256 + threadIdx.x;
    if (bin >= TOT) return;
    int d = off_bin[bin];
#pragma unroll
    for (int p = 0; p < NPART; ++p) {
        int s = offc2[p * TOT + bin];
        int e = offc2[p * TOT + bin + 1];
        for (int i = s; i < e; ++i) R2[d++] = R[i];
    }
}

// ---------------- MFMA bf16 GEMM: C = A @ Bn^T ----------------
__global__ __launch_bounds__(256) void gemm_mfma(
    const float* __restrict__ A, int M, int K, int lda,
    const unsigned short* __restrict__ Bn,
    float* __restrict__ C, int ldc, int mode,
    const float* __restrict__ sv, const float* __restrict__ tv,
    const float* __restrict__ node_embs, const int* __restrict__ flag)
{
    __shared__ unsigned short As[64 * 72];
    __shared__ unsigned short Bs[64 * 72];
    const int t = threadIdx.x;
    const int m0 = blockIdx.x * 64, n0 = blockIdx.y * 64;
    const int lane = t & 63, wave = t >> 6;
    const int wr = wave >> 1, wc = wave & 1;
    const int lrow = lane & 15, lkg = lane >> 4;

    f32x4 acc[2][2] = {};

    for (int kb = 0; kb < K; kb += 64) {
#pragma unroll
        for (int it = 0; it < 4; ++it) {
            int idx = t + it * 256;
            int kq = idx & 15;
            int row = idx >> 4;
            int gm = m0 + row;
            float4 a = make_float4(0.f, 0.f, 0.f, 0.f);
            if (gm < M) a = *(const float4*)(A + (size_t)gm * lda + kb + 4 * kq);
            unsigned int p0 = (unsigned int)f2bf(a.x) | ((unsigned int)f2bf(a.y) << 16);
            unsigned int p1 = (unsigned int)f2bf(a.z) | ((unsigned int)f2bf(a.w) << 16);
            *(uint2*)&As[row * 72 + 4 * kq] = make_uint2(p0, p1);
        }
#pragma unroll
        for (int it = 0; it < 2; ++it) {
            int idx = t + it * 256;
            int ko = idx & 7;
            int row = idx >> 3;
            uint4 b = *(const uint4*)(Bn + (size_t)(n0 + row) * K + kb + 8 * ko);
            *(uint4*)&Bs[row * 72 + 8 * ko] = b;
        }
        __syncthreads();
#pragma unroll
        for (int ks = 0; ks < 2; ++ks) {
            int k0 = ks * 32 + lkg * 8;
            bf16x8 af0 = *(const bf16x8*)&As[(wr * 32 + lrow) * 72 + k0];
            bf16x8 af1 = *(const bf16x8*)&As[(wr * 32 + 16 + lrow) * 72 + k0];
            bf16x8 bf0 = *(const bf16x8*)&Bs[(wc * 32 + lrow) * 72 + k0];
            bf16x8 bf1 = *(const bf16x8*)&Bs[(wc * 32 + 16 + lrow) * 72 + k0];
            acc[0][0] = __builtin_amdgcn_mfma_f32_16x16x32_bf16(af0, bf0, acc[0][0], 0, 0, 0);
            acc[0][1] = __builtin_amdgcn_mfma_f32_16x16x32_bf16(af0, bf1, acc[0][1], 0, 0, 0);
            acc[1][0] = __builtin_amdgcn_mfma_f32_16x16x32_bf16(af1, bf0, acc[1][0], 0, 0, 0);
            acc[1][1] = __builtin_amdgcn_mfma_f32_16x16x32_bf16(af1, bf1, acc[1][1], 0, 0, 0);
        }
        __syncthreads();
    }

#pragma unroll
    for (int m = 0; m < 2; ++m) {
#pragma unroll
        for (int r = 0; r < 4; ++r) {
            int gm = m0 + wr * 32 + m * 16 + lkg * 4 + r;
            if (gm >= M) continue;
#pragma unroll
            for (int n = 0; n < 2; ++n) {
                int gn = n0 + wc * 32 + n * 16 + lrow;
                float v = acc[m][n][r];
                if (mode == 0) {
                    C[(size_t)gm * ldc + gn] = v;
                } else if (mode == 1) {
                    float val = (gn >= 192) ? tanhf(v + sv[gn - 192]) : v;
                    C[(size_t)gm * ldc + gn] = val;
                } else {
                    float val = tanhf(v * sv[gn] + tv[gn]);
                    if (flag[0] == 0) val = node_embs[(size_t)gm * EMBD + gn];
                    C[(size_t)gm * EMBD + gn] = val;
                }
            }
        }
    }
}

// ---------------- CSR gather, quad-group float4 rows (r6 structure) ----------------

__device__ __forceinline__ void gather_quad(
    const unsigned* __restrict__ R, int r0, int r1, int g, int q,
    const float* __restrict__ TAB, int ldt, int toff,
    const float* __restrict__ ETAB, int eoff,
    float4& acc)
{
    int lane = g * 16 + q;
    int cnt = r1 - r0;
    for (int base = 0; base < cnt; base += 64) {
        int rem = cnt - base; if (rem > 64) rem = 64;
        unsigned rec = 0u;
        if (lane < rem) rec = R[r0 + base + lane];
        int i = 0;
        for (; 4 * i + 15 < rem; i += 4) {
            unsigned ra = __shfl(rec, 4 * i + g, 64);
            unsigned rb = __shfl(rec, 4 * i + 4 + g, 64);
            unsigned rc = __shfl(rec, 4 * i + 8 + g, 64);
            unsigned rd = __shfl(rec, 4 * i + 12 + g, 64);
            float4 a0 = *(const float4*)(TAB + (size_t)(ra & 0x7FFFu) * ldt + toff + 4 * q);
            float4 e0 = *(const float4*)(ETAB + (size_t)(ra >> 15) * 256 + eoff + 4 * q);
            float4 a1 = *(const float4*)(TAB + (size_t)(rb & 0x7FFFu) * ldt + toff + 4 * q);
            float4 e1 = *(const float4*)(ETAB + (size_t)(rb >> 15) * 256 + eoff + 4 * q);
            float4 a2 = *(const float4*)(TAB + (size_t)(rc & 0x7FFFu) * ldt + toff + 4 * q);
            float4 e2 = *(const float4*)(ETAB + (size_t)(rc >> 15) * 256 + eoff + 4 * q);
            float4 a3 = *(const float4*)(TAB + (size_t)(rd & 0x7FFFu) * ldt + toff + 4 * q);
            float4 e3 = *(const float4*)(ETAB + (size_t)(rd >> 15) * 256 + eoff + 4 * q);
            acc.x += (a0.x - e0.x) + (a1.x - e1.x) + (a2.x - e2.x) + (a3.x - e3.x);
            acc.y += (a0.y - e0.y) + (a1.y - e1.y) + (a2.y - e2.y) + (a3.y - e3.y);
            acc.z += (a0.z - e0.z) + (a1.z - e1.z) + (a2.z - e2.z) + (a3.z - e3.z);
            acc.w += (a0.w - e0.w) + (a1.w - e1.w) + (a2.w - e2.w) + (a3.w - e3.w);
        }
        for (; 4 * i < rem; ++i) {
            int idx = 4 * i + g;
            unsigned rr = __shfl(rec, idx < rem ? idx : 0, 64);
            if (idx < rem) {
                float4 a = *(const float4*)(TAB + (size_t)(rr & 0x7FFFu) * ldt + toff + 4 * q);
                float4 e = *(const float4*)(ETAB + (size_t)(rr >> 15) * 256 + eoff + 4 * q);
                acc.x += a.x - e.x; acc.y += a.y - e.y;
                acc.z += a.z - e.z; acc.w += a.w - e.w;
            }
        }
    }
}

__device__ __forceinline__ void xreduce(float4& v)
{
    v.x += __shfl_xor(v.x, 16, 64); v.y += __shfl_xor(v.y, 16, 64);
    v.z += __shfl_xor(v.z, 16, 64); v.w += __shfl_xor(v.w, 16, 64);
    v.x += __shfl_xor(v.x, 32, 64); v.y += __shfl_xor(v.y, 32, 64);
    v.z += __shfl_xor(v.z, 32, 64); v.w += __shfl_xor(v.w, 32, 64);
}

// layer 1 fused with combine: h1 = tanh((accO/deg_in + accI/deg_out + hS1raw)*s1 + t1)
__global__ __launch_bounds__(256) void k_gather1(
    const int* __restrict__ off_bin, const unsigned* __restrict__ R2,
    const float* __restrict__ C1, const float* __restrict__ E1,
    const float* __restrict__ s1, const float* __restrict__ t1,
    float* __restrict__ A2)
{
    int n = blockIdx.x * 4 + (threadIdx.x >> 6);
    if (n >= NN) return;
    int lane = threadIdx.x & 63, g = lane >> 4, q = lane & 15;
    int b0 = off_bin[n], b1 = off_bin[n + 1];
    int c0 = off_bin[NN + n], c1 = off_bin[NN + n + 1];
    float di = 1.f / fmaxf((float)(b1 - b0), 1.f);
    float dh = 1.f / fmaxf((float)(c1 - c0), 1.f);
    float4 accO = make_float4(0.f, 0.f, 0.f, 0.f);
    float4 accI = make_float4(0.f, 0.f, 0.f, 0.f);
    gather_quad(R2, b0, b1, g, q, C1, 192, 0, E1, 0, accO);
    gather_quad(R2, c0, c1, g, q, C1, 192, 64, E1, 64, accI);
    xreduce(accO);
    xreduce(accI);
    if (g == 0) {
        float4 hs = *(const float4*)(C1 + (size_t)n * 192 + 128 + 4 * q);
        float4 sv = *(const float4*)(s1 + 4 * q);
        float4 tv = *(const float4*)(t1 + 4 * q);
        float4 o;
        o.x = tanhf((accO.x * di + accI.x * dh + hs.x) * sv.x + tv.x);
        o.y = tanhf((accO.y * di + accI.y * dh + hs.y) * sv.y + tv.y);
        o.z = tanhf((accO.z * di + accI.z * dh + hs.z) * sv.z + tv.z);
        o.w = tanhf((accO.w * di + accI.w * dh + hs.w) * sv.w + tv.w);
        *(float4*)(A2 + (size_t)n * 192 + 128 + 4 * q) = o;
    }
}

// layer 2: both dirs read h1 (A2 cols[128,192)) minus er1 (E1 cols[192,256))
__global__ __launch_bounds__(256) void k_gather2(
    const int* __restrict__ off_bin, const unsigned* __restrict__ R2,
    const float* __restrict__ A2r, const float* __restrict__ E1,
    float* __restrict__ A2w)
{
    int n = blockIdx.x * 4 + (threadIdx.x >> 6);
    if (n >= NN) return;
    int lane = threadIdx.x & 63, g = lane >> 4, q = lane & 15;
    int b0 = off_bin[n], b1 = off_bin[n + 1];
    int c0 = off_bin[NN + n], c1 = off_bin[NN + n + 1];
    float di = 1.f / fmaxf((float)(b1 - b0), 1.f);
    float dh = 1.f / fmaxf((float)(c1 - c0), 1.f);
    float4 accO = make_float4(0.f, 0.f, 0.f, 0.f);
    float4 accI = make_float4(0.f, 0.f, 0.f, 0.f);
    gather_quad(R2, b0, b1, g, q, A2r, 192, 128, E1, 192, accO);
    gather_quad(R2, c0, c1, g, q, A2r, 192, 128, E1, 192, accI);
    xreduce(accO);
    xreduce(accI);
    if (g == 0) {
        float4 o0, o1;
        o0.x = accO.x * di; o0.y = accO.y * di; o0.z = accO.z * di; o0.w = accO.w * di;
        o1.x = accI.x * dh; o1.y = accI.y * dh; o1.z = accI.z * dh; o1.w = accI.w * dh;
        *(float4*)(A2w + (size_t)n * 192 + 4 * q) = o0;
        *(float4*)(A2w + (size_t)n * 192 + 64 + 4 * q) = o1;
    }
}

// ---------------- scoring ----------------
__global__ __launch_bounds__(64) void k_rels(
    const float* __restrict__ edge_embs,
    const float* __restrict__ Wr1, const float* __restrict__ br1,
    const float* __restrict__ Wr2, const float* __restrict__ br2,
    const int* __restrict__ hids, const int* __restrict__ rids, const int* __restrict__ tids,
    const int* __restrict__ is_head, const float* __restrict__ hn,
    float* __restrict__ tvec)
{
    __shared__ float e_s[256];
    __shared__ float m_s[64];
    int b = blockIdx.x, o = threadIdx.x;
    int rid = rids[b];
#pragma unroll
    for (int q = 0; q < 4; ++q) e_s[o + 64 * q] = edge_embs[(size_t)rid * 256 + o + 64 * q];
    __syncthreads();
    float acc = br1[o];
    for (int k = 0; k < 256; ++k) acc = fmaf(e_s[k], Wr1[o * 256 + k], acc);
    m_s[o] = fmaxf(acc, 0.f);
    __syncthreads();
    int ih = is_head[0];
    int nid = ih ? tids[b] : hids[b];
#pragma unroll
    for (int q = 0; q < 4; ++q) {
        int n = o + 64 * q;
        float r = br2[n];
        for (int jj = 0; jj < 64; ++jj) r = fmaf(m_s[jj], Wr2[n * 64 + jj], r);
        float hv = hn[(size_t)nid * 256 + n];
        tvec[b * 256 + n] = ih ? (hv - r) : (hv + r);
    }
}

__global__ __launch_bounds__(256) void k_score(
    const float* __restrict__ hn, const float* __restrict__ tvec,
    float* __restrict__ score)
{
    int p = blockIdx.x * 4 + (threadIdx.x >> 6);
    if (p >= BQ * (NN / BQ)) return;
    int l = threadIdx.x & 63;
    int b = p / (NN / BQ);
    int j = p - b * (NN / BQ);
    int idx = (b * NN + 32 * j) / BQ;   // faithful repeat_interleave indexing
    float ssum = 0.f;
#pragma unroll
    for (int q = 0; q < 4; ++q) {
        float df = hn[(size_t)idx * 256 + l + 64 * q] - tvec[b * 256 + l + 64 * q];
        ssum = fmaf(df, df, ssum);
    }
#pragma unroll
    for (int off = 32; off >= 1; off >>= 1) ssum += __shfl_xor(ssum, off, 64);
    float dist = sqrtf(ssum);
    float sc = 1.f / (1.f + expf(dist - 12.f));
    if (l < 32) score[(size_t)b * NN + 32 * j + l] = sc;
}

// ---------------- launch ----------------
extern "C" void kernel_launch(void* const* d_in, const int* in_sizes, int n_in,
                              void* d_out, int out_size, void* d_ws, size_t ws_size,
                              hipStream_t stream)
{
    const float* node_embs = (const float*)d_in[0];
    const float* edge_embs = (const float*)d_in[1];
    const float* W_O1 = (const float*)d_in[2];  const float* b_O1 = (const float*)d_in[3];
    const float* W_I1 = (const float*)d_in[4];  const float* b_I1 = (const float*)d_in[5];
    const float* W_S1 = (const float*)d_in[6];  const float* b_S1 = (const float*)d_in[7];
    const float* bn1_g = (const float*)d_in[8]; const float* bn1_b = (const float*)d_in[9];
    const float* bn1_m = (const float*)d_in[10];const float* bn1_v = (const float*)d_in[11];
    const float* Wr1 = (const float*)d_in[12];  const float* br1 = (const float*)d_in[13];
    const float* W_O2 = (const float*)d_in[14]; const float* b_O2 = (const float*)d_in[15];
    const float* W_I2 = (const float*)d_in[16]; const float* b_I2 = (const float*)d_in[17];
    const float* W_S2 = (const float*)d_in[18]; const float* b_S2 = (const float*)d_in[19];
    const float* bn2_g = (const float*)d_in[20];const float* bn2_b = (const float*)d_in[21];
    const float* bn2_m = (const float*)d_in[22];const float* bn2_v = (const float*)d_in[23];
    const float* Wr2 = (const float*)d_in[24];  const float* br2 = (const float*)d_in[25];
    const int* src = (const int*)d_in[26];
    const int* dst = (const int*)d_in[27];
    const int* evid = (const int*)d_in[28];
    const int* hids = (const int*)d_in[29];
    const int* rids = (const int*)d_in[30];
    const int* tids = (const int*)d_in[31];
    const int* upd = (const int*)d_in[32];
    const int* ihead = (const int*)d_in[33];

    float* ws = (float*)d_ws;
    float* C1   = ws;                      // 20000*192
    float* A2   = C1 + 3840000;            // 20000*192
    float* E1   = A2 + 3840000;            // 500*256
    unsigned short* Bn1 = (unsigned short*)(E1 + 128000);  // 256*256 bf16
    unsigned short* Bn2 = Bn1 + 65536;                     // 256*192 bf16
    float* s1   = (float*)(Bn2 + 49152);   // 64
    float* t1   = s1 + 64;                 // 64
    float* s2   = t1 + 64;                 // 256
    float* t2   = s2 + 256;                // 256
    float* tvec = t2 + 256;                // 32*256

    unsigned* R   = (unsigned*)(tvec + 8192);  // 2*NE partition-major records
    unsigned* R2  = R + 2 * NE;                // 2*NE bin-major records
    int* cnt2     = (int*)(R2 + 2 * NE);       // TOT2
    int* offc2    = cnt2 + TOT2;               // TOT2+1
    int* cur2     = offc2 + TOT2 + 1;          // TOT2
    int* binTotal = cur2 + TOT2;               // TOT
    int* off_bin  = binTotal + TOT;            // TOT+1
    int* bsum     = off_bin + TOT + 1;         // NB2
    int* bsum2    = bsum + NB2;                // NB3

    float* hn    = (float*)d_out;                       // 20000*256
    float* score = hn + (size_t)NN * EMBD;              // 32*20000

    hipMemsetAsync(cnt2, 0, (size_t)TOT2 * 4, stream);

    k_buildBn<<<NBLK_BN + 2, 256, 0, stream>>>(
        W_O1, W_I1, W_S1, Wr1, W_O2, W_I2, W_S2, Bn1, Bn2,
        b_O1, b_I1, b_S1, bn1_g, bn1_b, bn1_m, bn1_v,
        b_O2, b_I2, b_S2, bn2_g, bn2_b, bn2_m, bn2_v,
        s1, t1, s2, t2);

    // partitioned CSR build + bin-major repack
    k_hist<<<(NE + 255) / 256, 256, 0, stream>>>(src, dst, cnt2);
    k_scanA<<<NB2, 256, 0, stream>>>(cnt2, bsum, TOT2);
    k_sumbins<<<(TOT + 255) / 256, 256, 0, stream>>>(cnt2, binTotal);
    k_scanA<<<NB3, 256, 0, stream>>>(binTotal, bsum2, TOT);
    k_scanB<<<1, 64, 0, stream>>>(bsum, NB2);
    k_scanB<<<1, 64, 0, stream>>>(bsum2, NB3);
    k_scanC<<<NB2, 256, 0, stream>>>(cnt2, bsum, offc2, cur2, TOT2, 2 * NE, 1);
    k_scanC<<<NB3, 256, 0, stream>>>(binTotal, bsum2, off_bin, nullptr, TOT, 2 * NE, 0);
    k_scatter<<<(NE + 255) / 256, 256, 0, stream>>>(src, dst, evid, cur2, R);
    k_repack<<<(TOT + 255) / 256, 256, 0, stream>>>(offc2, off_bin, R, R2);

    // C1 = node_embs @ Bn1[0:192]^T   (M=20000, K=256)
    gemm_mfma<<<dim3(313, 3), 256, 0, stream>>>(node_embs, NN, 256, 256, Bn1,
                                                C1, 192, 0, nullptr, nullptr, nullptr, nullptr);
    // E1 = edge_embs @ Bn1^T, fused er1 on cols [192,256)   (M=500, K=256)
    gemm_mfma<<<dim3(8, 4), 256, 0, stream>>>(edge_embs, NR, 256, 256, Bn1,
                                              E1, 256, 1, br1, nullptr, nullptr, nullptr);

    // layer-1 aggregation + combine (writes h1 into A2 cols [128,192))
    k_gather1<<<NN / 4, 256, 0, stream>>>(off_bin, R2, C1, E1, s1, t1, A2);
    // layer-2 aggregation (writes A2 cols [0,128))
    k_gather2<<<NN / 4, 256, 0, stream>>>(off_bin, R2, A2, E1, A2);

    // hn = tanh((A2 @ Bn2^T) * s2 + t2)  (or node_embs if !upd)  (M=20000, K=192)
    gemm_mfma<<<dim3(313, 4), 256, 0, stream>>>(A2, NN, 192, 192, Bn2,
                                                hn, 256, 2, s2, t2, node_embs, upd);

    k_rels<<<BQ, 64, 0, stream>>>(edge_embs, Wr1, br1, Wr2, br2,
                                  hids, rids, tids, ihead, hn, tvec);
    k_score<<<(BQ * (NN / BQ)) / 4, 256, 0, stream>>>(hn, tvec, score);
}

// Round 9
// 171.971 us; speedup vs baseline: 1.2262x; 1.2262x over previous
//
#include <hip/hip_runtime.h>
#include <math.h>

#define NN 20000     // nodes
#define NE 320000    // edges
#define NR 500       // relations
#define EMBD 256
#define D4 64
#define BQ 32        // batch
#define TOT (2 * NN) // concatenated count length
#define NB 40        // scan blocks (40*1024 >= TOT)

#define NBLK_HIST 1250           // (NE+255)/256
#define NBLK_BN 448              // weight-pack blocks
#define NBLK_K1 (NBLK_HIST + NBLK_BN + 2)

#define NBLK_GC1 939             // 313*3 C1-GEMM blocks
#define NBLK_GE1 32              // 8*4 E1-GEMM blocks
#define NBLK_MEGA (NBLK_GC1 + NBLK_GE1 + NBLK_HIST)

typedef __attribute__((ext_vector_type(8))) short bf16x8;
typedef __attribute__((ext_vector_type(4))) float f32x4;

__device__ __forceinline__ unsigned short f2bf(float x)
{
    unsigned int u = __float_as_uint(x);
    unsigned int r = (u + 0x7fffu + ((u >> 16) & 1u)) >> 16;   // RNE
    return (unsigned short)r;
}

// ---------------- K1: hist + weight pack + params (independent work fused) ----------------
__global__ __launch_bounds__(256) void k_prep(
    const int* __restrict__ src, const int* __restrict__ dst, int* __restrict__ cnt,
    const float* __restrict__ W_O1, const float* __restrict__ W_I1,
    const float* __restrict__ W_S1, const float* __restrict__ Wr1,
    const float* __restrict__ W_O2, const float* __restrict__ W_I2,
    const float* __restrict__ W_S2,
    unsigned short* __restrict__ Bn1, unsigned short* __restrict__ Bn2,
    const float* __restrict__ bO1, const float* __restrict__ bI1,
    const float* __restrict__ bS1,
    const float* __restrict__ g1, const float* __restrict__ bb1,
    const float* __restrict__ m1, const float* __restrict__ v1,
    const float* __restrict__ bO2, const float* __restrict__ bI2,
    const float* __restrict__ bS2,
    const float* __restrict__ g2, const float* __restrict__ bb2,
    const float* __restrict__ m2, const float* __restrict__ v2,
    float* __restrict__ s1, float* __restrict__ t1,
    float* __restrict__ s2, float* __restrict__ t2)
{
    int b = blockIdx.x;
    if (b < NBLK_HIST) {
        int i = b * 256 + threadIdx.x;
        if (i < NE) {
            atomicAdd(&cnt[dst[i]], 1);
            atomicAdd(&cnt[NN + src[i]], 1);
        }
        return;
    }
    b -= NBLK_HIST;
    if (b >= NBLK_BN) {
        int i = (b - NBLK_BN) * 256 + threadIdx.x;   // [0,512)
        if (i < 64) {
            float rsg = g1[i] / sqrtf(v1[i] + 1e-5f);
            s1[i] = rsg * (1.f / 3.f);
            t1[i] = ((bO1[i] + bI1[i] + bS1[i]) * (1.f / 3.f) - m1[i]) * rsg + bb1[i];
        } else if (i < 320) {
            int n = i - 64;
            float rsg = g2[n] / sqrtf(v2[n] + 1e-5f);
            s2[n] = rsg * (1.f / 3.f);
            t2[n] = ((bO2[n] + bI2[n] + bS2[n]) * (1.f / 3.f) - m2[n]) * rsg + bb2[n];
        }
        return;
    }
    int id = b * 256 + threadIdx.x;
    if (id < 256 * 256) {
        int n = id >> 8, k = id & 255;
        float v;
        if (n < 64)       v = W_O1[n * 256 + k];
        else if (n < 128) v = W_I1[(n - 64) * 256 + k];
        else if (n < 192) v = W_S1[(n - 128) * 256 + k];
        else              v = Wr1[(n - 192) * 256 + k];
        Bn1[id] = f2bf(v);
    } else {
        int id2 = id - 256 * 256;
        if (id2 < 256 * 192) {
            int n = id2 / 192, k = id2 - n * 192;
            float v;
            if (k < 64)       v = W_O2[n * 64 + k];
            else if (k < 128) v = W_I2[n * 64 + (k - 64)];
            else              v = W_S2[n * 64 + (k - 128)];
            Bn2[id2] = f2bf(v);
        }
    }
}

// ---------------- scan pipeline (r6) ----------------

__global__ __launch_bounds__(256) void k_scanA(const int* __restrict__ cnt,
                                               int* __restrict__ bsum)
{
    __shared__ int lds[256];
    int t = threadIdx.x;
    int base = blockIdx.x * 1024 + t * 4;
    int s = 0;
    if (base + 3 < TOT) {
        int4 v = *(const int4*)(cnt + base);
        s = v.x + v.y + v.z + v.w;
    } else {
        for (int c = 0; c < 4; ++c) { int i = base + c; if (i < TOT) s += cnt[i]; }
    }
    lds[t] = s;
    __syncthreads();
    for (int d = 128; d > 0; d >>= 1) {
        if (t < d) lds[t] += lds[t + d];
        __syncthreads();
    }
    if (t == 0) bsum[blockIdx.x] = lds[0];
}

__global__ __launch_bounds__(64) void k_scanB(int* __restrict__ bsum)
{
    int t = threadIdx.x;
    int v = (t < NB) ? bsum[t] : 0;
#pragma unroll
    for (int d = 1; d < 64; d <<= 1) {
        int u = __shfl_up(v, d, 64);
        if (t >= d) v += u;
    }
    int ex = __shfl_up(v, 1, 64);
    if (t == 0) ex = 0;
    if (t < NB) bsum[t] = ex;
}

__global__ __launch_bounds__(256) void k_scanC(const int* __restrict__ cnt,
                                               const int* __restrict__ bsum,
                                               int* __restrict__ offc,
                                               int* __restrict__ cur)
{
    __shared__ int lds[256];
    int t = threadIdx.x;
    int base = blockIdx.x * 1024 + t * 4;
    int e0 = 0, e1 = 0, e2 = 0, e3 = 0;
    if (base + 3 < TOT) {
        int4 v = *(const int4*)(cnt + base);
        e0 = v.x; e1 = v.y; e2 = v.z; e3 = v.w;
    } else {
        if (base + 0 < TOT) e0 = cnt[base + 0];
        if (base + 1 < TOT) e1 = cnt[base + 1];
        if (base + 2 < TOT) e2 = cnt[base + 2];
        if (base + 3 < TOT) e3 = cnt[base + 3];
    }
    int s = e0 + e1 + e2 + e3;
    lds[t] = s;
    __syncthreads();
    for (int d = 1; d < 256; d <<= 1) {
        int u = (t >= d) ? lds[t - d] : 0;
        __syncthreads();
        lds[t] += u;
        __syncthreads();
    }
    int run = lds[t] - s + bsum[blockIdx.x];
    if (base + 3 < TOT) {
        int4 o = make_int4(run, run + e0, run + e0 + e1, run + e0 + e1 + e2);
        *(int4*)(offc + base) = o;
        *(int4*)(cur + base) = o;
    } else {
        int r = run;
        if (base + 0 < TOT) { offc[base + 0] = r; cur[base + 0] = r; r += e0; }
        if (base + 1 < TOT) { offc[base + 1] = r; cur[base + 1] = r; r += e1; }
        if (base + 2 < TOT) { offc[base + 2] = r; cur[base + 2] = r; r += e2; }
        if (base + 3 < TOT) { offc[base + 3] = r; cur[base + 3] = r; r += e3; }
    }
    if (blockIdx.x == 0 && t == 0) offc[TOT] = 2 * NE;
}

// ---------------- MFMA bf16 GEMM body (device fn) ----------------
// mode 0: raw f32 store (ldc). mode 1: E1 epilogue (tanh(v+sv[gn-192]) for gn>=192).
// mode 2: hn epilogue tanh(acc*sv+tv) / node_embs passthrough.
__device__ __forceinline__ void gemm_dev(
    unsigned short* As, unsigned short* Bs,
    const float* __restrict__ A, int M, int K, int lda,
    const unsigned short* __restrict__ Bn,
    float* __restrict__ C, int ldc, int mode,
    const float* __restrict__ sv, const float* __restrict__ tv,
    const float* __restrict__ node_embs, const int* __restrict__ flag,
    int m0, int n0)
{
    const int t = threadIdx.x;
    const int lane = t & 63, wave = t >> 6;
    const int wr = wave >> 1, wc = wave & 1;
    const int lrow = lane & 15, lkg = lane >> 4;

    f32x4 acc[2][2] = {};

    for (int kb = 0; kb < K; kb += 64) {
#pragma unroll
        for (int it = 0; it < 4; ++it) {
            int idx = t + it * 256;
            int kq = idx & 15;
            int row = idx >> 4;
            int gm = m0 + row;
            float4 a = make_float4(0.f, 0.f, 0.f, 0.f);
            if (gm < M) a = *(const float4*)(A + (size_t)gm * lda + kb + 4 * kq);
            unsigned int p0 = (unsigned int)f2bf(a.x) | ((unsigned int)f2bf(a.y) << 16);
            unsigned int p1 = (unsigned int)f2bf(a.z) | ((unsigned int)f2bf(a.w) << 16);
            *(uint2*)&As[row * 72 + 4 * kq] = make_uint2(p0, p1);
        }
#pragma unroll
        for (int it = 0; it < 2; ++it) {
            int idx = t + it * 256;
            int ko = idx & 7;
            int row = idx >> 3;
            uint4 b = *(const uint4*)(Bn + (size_t)(n0 + row) * K + kb + 8 * ko);
            *(uint4*)&Bs[row * 72 + 8 * ko] = b;
        }
        __syncthreads();
#pragma unroll
        for (int ks = 0; ks < 2; ++ks) {
            int k0 = ks * 32 + lkg * 8;
            bf16x8 af0 = *(const bf16x8*)&As[(wr * 32 + lrow) * 72 + k0];
            bf16x8 af1 = *(const bf16x8*)&As[(wr * 32 + 16 + lrow) * 72 + k0];
            bf16x8 bf0 = *(const bf16x8*)&Bs[(wc * 32 + lrow) * 72 + k0];
            bf16x8 bf1 = *(const bf16x8*)&Bs[(wc * 32 + 16 + lrow) * 72 + k0];
            acc[0][0] = __builtin_amdgcn_mfma_f32_16x16x32_bf16(af0, bf0, acc[0][0], 0, 0, 0);
            acc[0][1] = __builtin_amdgcn_mfma_f32_16x16x32_bf16(af0, bf1, acc[0][1], 0, 0, 0);
            acc[1][0] = __builtin_amdgcn_mfma_f32_16x16x32_bf16(af1, bf0, acc[1][0], 0, 0, 0);
            acc[1][1] = __builtin_amdgcn_mfma_f32_16x16x32_bf16(af1, bf1, acc[1][1], 0, 0, 0);
        }
        __syncthreads();
    }

#pragma unroll
    for (int m = 0; m < 2; ++m) {
#pragma unroll
        for (int r = 0; r < 4; ++r) {
            int gm = m0 + wr * 32 + m * 16 + lkg * 4 + r;
            if (gm >= M) continue;
#pragma unroll
            for (int n = 0; n < 2; ++n) {
                int gn = n0 + wc * 32 + n * 16 + lrow;
                float v = acc[m][n][r];
                if (mode == 0) {
                    C[(size_t)gm * ldc + gn] = v;
                } else if (mode == 1) {
                    float val = (gn >= 192) ? tanhf(v + sv[gn - 192]) : v;
                    C[(size_t)gm * ldc + gn] = val;
                } else {
                    float val = tanhf(v * sv[gn] + tv[gn]);
                    if (flag[0] == 0) val = node_embs[(size_t)gm * EMBD + gn];
                    C[(size_t)gm * EMBD + gn] = val;
                }
            }
        }
    }
}

// standalone GEMM kernel (final hn GEMM)
__global__ __launch_bounds__(256) void gemm_mfma(
    const float* __restrict__ A, int M, int K, int lda,
    const unsigned short* __restrict__ Bn,
    float* __restrict__ C, int ldc, int mode,
    const float* __restrict__ sv, const float* __restrict__ tv,
    const float* __restrict__ node_embs, const int* __restrict__ flag)
{
    __shared__ unsigned short As[64 * 72];
    __shared__ unsigned short Bs[64 * 72];
    gemm_dev(As, Bs, A, M, K, lda, Bn, C, ldc, mode, sv, tv, node_embs, flag,
             blockIdx.x * 64, blockIdx.y * 64);
}

// ---------------- K5: scatter || C1-GEMM || E1-GEMM (mega fusion) ----------------
__global__ __launch_bounds__(256) void k_mega(
    const float* __restrict__ node_embs, const float* __restrict__ edge_embs,
    const unsigned short* __restrict__ Bn1,
    float* __restrict__ C1, float* __restrict__ E1, const float* __restrict__ br1,
    const int* __restrict__ src, const int* __restrict__ dst,
    const int* __restrict__ evid,
    int* __restrict__ cur, unsigned* __restrict__ R)
{
    __shared__ unsigned short As[64 * 72];
    __shared__ unsigned short Bs[64 * 72];
    int bid = blockIdx.x;
    if (bid < NBLK_GC1) {
        // C1 = node_embs @ Bn1[0:192]^T
        gemm_dev(As, Bs, node_embs, NN, 256, 256, Bn1, C1, 192, 0,
                 nullptr, nullptr, nullptr, nullptr,
                 (bid % 313) * 64, (bid / 313) * 64);
    } else if (bid < NBLK_GC1 + NBLK_GE1) {
        // E1 = edge_embs @ Bn1^T (+ fused er1 tanh on cols [192,256))
        int b2 = bid - NBLK_GC1;
        gemm_dev(As, Bs, edge_embs, NR, 256, 256, Bn1, E1, 256, 1,
                 br1, nullptr, nullptr, nullptr,
                 (b2 % 8) * 64, (b2 / 8) * 64);
    } else {
        int e = (bid - NBLK_GC1 - NBLK_GE1) * 256 + threadIdx.x;
        if (e < NE) {
            int s = src[e], d = dst[e];
            unsigned rv = (unsigned)evid[e] << 15;
            int p = atomicAdd(&cur[d], 1);
            R[p] = (unsigned)s | rv;
            int q = atomicAdd(&cur[NN + s], 1);
            R[q] = (unsigned)d | rv;
        }
    }
}

// ---------------- CSR gather, quad-group float4 rows (r6 structure) ----------------

__device__ __forceinline__ void gather_quad(
    const unsigned* __restrict__ R, int r0, int r1, int g, int q,
    const float* __restrict__ TAB, int ldt, int toff,
    const float* __restrict__ ETAB, int eoff,
    float4& acc)
{
    int lane = g * 16 + q;
    int cnt = r1 - r0;
    for (int base = 0; base < cnt; base += 64) {
        int rem = cnt - base; if (rem > 64) rem = 64;
        unsigned rec = 0u;
        if (lane < rem) rec = R[r0 + base + lane];
        int i = 0;
        for (; 4 * i + 15 < rem; i += 4) {
            unsigned ra = __shfl(rec, 4 * i + g, 64);
            unsigned rb = __shfl(rec, 4 * i + 4 + g, 64);
            unsigned rc = __shfl(rec, 4 * i + 8 + g, 64);
            unsigned rd = __shfl(rec, 4 * i + 12 + g, 64);
            float4 a0 = *(const float4*)(TAB + (size_t)(ra & 0x7FFFu) * ldt + toff + 4 * q);
            float4 e0 = *(const float4*)(ETAB + (size_t)(ra >> 15) * 256 + eoff + 4 * q);
            float4 a1 = *(const float4*)(TAB + (size_t)(rb & 0x7FFFu) * ldt + toff + 4 * q);
            float4 e1 = *(const float4*)(ETAB + (size_t)(rb >> 15) * 256 + eoff + 4 * q);
            float4 a2 = *(const float4*)(TAB + (size_t)(rc & 0x7FFFu) * ldt + toff + 4 * q);
            float4 e2 = *(const float4*)(ETAB + (size_t)(rc >> 15) * 256 + eoff + 4 * q);
            float4 a3 = *(const float4*)(TAB + (size_t)(rd & 0x7FFFu) * ldt + toff + 4 * q);
            float4 e3 = *(const float4*)(ETAB + (size_t)(rd >> 15) * 256 + eoff + 4 * q);
            acc.x += (a0.x - e0.x) + (a1.x - e1.x) + (a2.x - e2.x) + (a3.x - e3.x);
            acc.y += (a0.y - e0.y) + (a1.y - e1.y) + (a2.y - e2.y) + (a3.y - e3.y);
            acc.z += (a0.z - e0.z) + (a1.z - e1.z) + (a2.z - e2.z) + (a3.z - e3.z);
            acc.w += (a0.w - e0.w) + (a1.w - e1.w) + (a2.w - e2.w) + (a3.w - e3.w);
        }
        for (; 4 * i < rem; ++i) {
            int idx = 4 * i + g;
            unsigned rr = __shfl(rec, idx < rem ? idx : 0, 64);
            if (idx < rem) {
                float4 a = *(const float4*)(TAB + (size_t)(rr & 0x7FFFu) * ldt + toff + 4 * q);
                float4 e = *(const float4*)(ETAB + (size_t)(rr >> 15) * 256 + eoff + 4 * q);
                acc.x += a.x - e.x; acc.y += a.y - e.y;
                acc.z += a.z - e.z; acc.w += a.w - e.w;
            }
        }
    }
}

__device__ __forceinline__ void xreduce(float4& v)
{
    v.x += __shfl_xor(v.x, 16, 64); v.y += __shfl_xor(v.y, 16, 64);
    v.z += __shfl_xor(v.z, 16, 64); v.w += __shfl_xor(v.w, 16, 64);
    v.x += __shfl_xor(v.x, 32, 64); v.y += __shfl_xor(v.y, 32, 64);
    v.z += __shfl_xor(v.z, 32, 64); v.w += __shfl_xor(v.w, 32, 64);
}

// layer 1 fused with combine: h1 = tanh((accO/deg_in + accI/deg_out + hS1raw)*s1 + t1)
__global__ __launch_bounds__(256) void k_gather1(
    const int* __restrict__ offc, const unsigned* __restrict__ R,
    const float* __restrict__ C1, const float* __restrict__ E1,
    const float* __restrict__ s1, const float* __restrict__ t1,
    float* __restrict__ A2)
{
    int n = blockIdx.x * 4 + (threadIdx.x >> 6);
    if (n >= NN) return;
    int lane = threadIdx.x & 63, g = lane >> 4, q = lane & 15;
    int b0 = offc[n], b1 = offc[n + 1];
    int c0 = offc[NN + n], c1 = offc[NN + n + 1];
    float di = 1.f / fmaxf((float)(b1 - b0), 1.f);
    float dh = 1.f / fmaxf((float)(c1 - c0), 1.f);
    float4 accO = make_float4(0.f, 0.f, 0.f, 0.f);
    float4 accI = make_float4(0.f, 0.f, 0.f, 0.f);
    gather_quad(R, b0, b1, g, q, C1, 192, 0, E1, 0, accO);
    gather_quad(R, c0, c1, g, q, C1, 192, 64, E1, 64, accI);
    xreduce(accO);
    xreduce(accI);
    if (g == 0) {
        float4 hs = *(const float4*)(C1 + (size_t)n * 192 + 128 + 4 * q);
        float4 sv = *(const float4*)(s1 + 4 * q);
        float4 tv = *(const float4*)(t1 + 4 * q);
        float4 o;
        o.x = tanhf((accO.x * di + accI.x * dh + hs.x) * sv.x + tv.x);
        o.y = tanhf((accO.y * di + accI.y * dh + hs.y) * sv.y + tv.y);
        o.z = tanhf((accO.z * di + accI.z * dh + hs.z) * sv.z + tv.z);
        o.w = tanhf((accO.w * di + accI.w * dh + hs.w) * sv.w + tv.w);
        *(float4*)(A2 + (size_t)n * 192 + 128 + 4 * q) = o;
    }
}

// layer 2: both dirs read h1 (A2 cols[128,192)) minus er1 (E1 cols[192,256))
__global__ __launch_bounds__(256) void k_gather2(
    const int* __restrict__ offc, const unsigned* __restrict__ R,
    const float* __restrict__ A2r, const float* __restrict__ E1,
    float* __restrict__ A2w)
{
    int n = blockIdx.x * 4 + (threadIdx.x >> 6);
    if (n >= NN) return;
    int lane = threadIdx.x & 63, g = lane >> 4, q = lane & 15;
    int b0 = offc[n], b1 = offc[n + 1];
    int c0 = offc[NN + n], c1 = offc[NN + n + 1];
    float di = 1.f / fmaxf((float)(b1 - b0), 1.f);
    float dh = 1.f / fmaxf((float)(c1 - c0), 1.f);
    float4 accO = make_float4(0.f, 0.f, 0.f, 0.f);
    float4 accI = make_float4(0.f, 0.f, 0.f, 0.f);
    gather_quad(R, b0, b1, g, q, A2r, 192, 128, E1, 192, accO);
    gather_quad(R, c0, c1, g, q, A2r, 192, 128, E1, 192, accI);
    xreduce(accO);
    xreduce(accI);
    if (g == 0) {
        float4 o0, o1;
        o0.x = accO.x * di; o0.y = accO.y * di; o0.z = accO.z * di; o0.w = accO.w * di;
        o1.x = accI.x * dh; o1.y = accI.y * dh; o1.z = accI.z * dh; o1.w = accI.w * dh;
        *(float4*)(A2w + (size_t)n * 192 + 4 * q) = o0;
        *(float4*)(A2w + (size_t)n * 192 + 64 + 4 * q) = o1;
    }
}

// ---------------- scoring ----------------
__global__ __launch_bounds__(64) void k_rels(
    const float* __restrict__ edge_embs,
    const float* __restrict__ Wr1, const float* __restrict__ br1,
    const float* __restrict__ Wr2, const float* __restrict__ br2,
    const int* __restrict__ hids, const int* __restrict__ rids, const int* __restrict__ tids,
    const int* __restrict__ is_head, const float* __restrict__ hn,
    float* __restrict__ tvec)
{
    __shared__ float e_s[256];
    __shared__ float m_s[64];
    int b = blockIdx.x, o = threadIdx.x;
    int rid = rids[b];
#pragma unroll
    for (int q = 0; q < 4; ++q) e_s[o + 64 * q] = edge_embs[(size_t)rid * 256 + o + 64 * q];
    __syncthreads();
    float acc = br1[o];
    for (int k = 0; k < 256; ++k) acc = fmaf(e_s[k], Wr1[o * 256 + k], acc);
    m_s[o] = fmaxf(acc, 0.f);
    __syncthreads();
    int ih = is_head[0];
    int nid = ih ? tids[b] : hids[b];
#pragma unroll
    for (int q = 0; q < 4; ++q) {
        int n = o + 64 * q;
        float r = br2[n];
        for (int jj = 0; jj < 64; ++jj) r = fmaf(m_s[jj], Wr2[n * 64 + jj], r);
        float hv = hn[(size_t)nid * 256 + n];
        tvec[b * 256 + n] = ih ? (hv - r) : (hv + r);
    }
}

__global__ __launch_bounds__(256) void k_score(
    const float* __restrict__ hn, const float* __restrict__ tvec,
    float* __restrict__ score)
{
    int p = blockIdx.x * 4 + (threadIdx.x >> 6);
    if (p >= BQ * (NN / BQ)) return;
    int l = threadIdx.x & 63;
    int b = p / (NN / BQ);
    int j = p - b * (NN / BQ);
    int idx = (b * NN + 32 * j) / BQ;   // faithful repeat_interleave indexing
    float ssum = 0.f;
#pragma unroll
    for (int q = 0; q < 4; ++q) {
        float df = hn[(size_t)idx * 256 + l + 64 * q] - tvec[b * 256 + l + 64 * q];
        ssum = fmaf(df, df, ssum);
    }
#pragma unroll
    for (int off = 32; off >= 1; off >>= 1) ssum += __shfl_xor(ssum, off, 64);
    float dist = sqrtf(ssum);
    float sc = 1.f / (1.f + expf(dist - 12.f));
    if (l < 32) score[(size_t)b * NN + 32 * j + l] = sc;
}

// ---------------- launch ----------------
extern "C" void kernel_launch(void* const* d_in, const int* in_sizes, int n_in,
                              void* d_out, int out_size, void* d_ws, size_t ws_size,
                              hipStream_t stream)
{
    const float* node_embs = (const float*)d_in[0];
    const float* edge_embs = (const float*)d_in[1];
    const float* W_O1 = (const float*)d_in[2];  const float* b_O1 = (const float*)d_in[3];
    const float* W_I1 = (const float*)d_in[4];  const float* b_I1 = (const float*)d_in[5];
    const float* W_S1 = (const float*)d_in[6];  const float* b_S1 = (const float*)d_in[7];
    const float* bn1_g = (const float*)d_in[8]; const float* bn1_b = (const float*)d_in[9];
    const float* bn1_m = (const float*)d_in[10];const float* bn1_v = (const float*)d_in[11];
    const float* Wr1 = (const float*)d_in[12];  const float* br1 = (const float*)d_in[13];
    const float* W_O2 = (const float*)d_in[14]; const float* b_O2 = (const float*)d_in[15];
    const float* W_I2 = (const float*)d_in[16]; const float* b_I2 = (const float*)d_in[17];
    const float* W_S2 = (const float*)d_in[18]; const float* b_S2 = (const float*)d_in[19];
    const float* bn2_g = (const float*)d_in[20];const float* bn2_b = (const float*)d_in[21];
    const float* bn2_m = (const float*)d_in[22];const float* bn2_v = (const float*)d_in[23];
    const float* Wr2 = (const float*)d_in[24];  const float* br2 = (const float*)d_in[25];
    const int* src = (const int*)d_in[26];
    const int* dst = (const int*)d_in[27];
    const int* evid = (const int*)d_in[28];
    const int* hids = (const int*)d_in[29];
    const int* rids = (const int*)d_in[30];
    const int* tids = (const int*)d_in[31];
    const int* upd = (const int*)d_in[32];
    const int* ihead = (const int*)d_in[33];

    float* ws = (float*)d_ws;
    float* C1   = ws;                      // 20000*192
    float* A2   = C1 + 3840000;            // 20000*192
    float* E1   = A2 + 3840000;            // 500*256
    unsigned short* Bn1 = (unsigned short*)(E1 + 128000);  // 256*256 bf16
    unsigned short* Bn2 = Bn1 + 65536;                     // 256*192 bf16
    float* s1   = (float*)(Bn2 + 49152);   // 64
    float* t1   = s1 + 64;                 // 64
    float* s2   = t1 + 64;                 // 256
    float* t2   = s2 + 256;                // 256
    float* tvec = t2 + 256;                // 32*256

    unsigned* R = (unsigned*)(tvec + 8192);// 2*NE packed records
    int* cnt    = (int*)(R + 2 * NE);      // TOT
    int* offc   = cnt + TOT;               // TOT+1
    int* cur    = offc + TOT + 1;          // TOT
    int* bsum   = cur + TOT;               // NB

    float* hn    = (float*)d_out;                       // 20000*256
    float* score = hn + (size_t)NN * EMBD;              // 32*20000

    hipMemsetAsync(cnt, 0, (size_t)TOT * 4, stream);

    // K1: hist || weight-pack || params
    k_prep<<<NBLK_K1, 256, 0, stream>>>(
        src, dst, cnt,
        W_O1, W_I1, W_S1, Wr1, W_O2, W_I2, W_S2, Bn1, Bn2,
        b_O1, b_I1, b_S1, bn1_g, bn1_b, bn1_m, bn1_v,
        b_O2, b_I2, b_S2, bn2_g, bn2_b, bn2_m, bn2_v,
        s1, t1, s2, t2);

    // scan pipeline
    k_scanA<<<NB, 256, 0, stream>>>(cnt, bsum);
    k_scanB<<<1, 64, 0, stream>>>(bsum);
    k_scanC<<<NB, 256, 0, stream>>>(cnt, bsum, offc, cur);

    // K5: scatter || C1-GEMM || E1-GEMM
    k_mega<<<NBLK_MEGA, 256, 0, stream>>>(node_embs, edge_embs, Bn1,
                                          C1, E1, br1, src, dst, evid, cur, R);

    // layer-1 aggregation + combine (writes h1 into A2 cols [128,192))
    k_gather1<<<NN / 4, 256, 0, stream>>>(offc, R, C1, E1, s1, t1, A2);
    // layer-2 aggregation (writes A2 cols [0,128))
    k_gather2<<<NN / 4, 256, 0, stream>>>(offc, R, A2, E1, A2);

    // hn = tanh((A2 @ Bn2^T) * s2 + t2)  (or node_embs if !upd)  (M=20000, K=192)
    gemm_mfma<<<dim3(313, 4), 256, 0, stream>>>(A2, NN, 192, 192, Bn2,
                                                hn, 256, 2, s2, t2, node_embs, upd);

    k_rels<<<BQ, 64, 0, stream>>>(edge_embs, Wr1, br1, Wr2, br2,
                                  hids, rids, tids, ihead, hn, tvec);
    k_score<<<(BQ * (NN / BQ)) / 4, 256, 0, stream>>>(hn, tvec, score);
}

// Round 10
// 143.222 us; speedup vs baseline: 1.4724x; 1.2007x over previous
//
#include <hip/hip_runtime.h>
#include <math.h>

#define NN 20000     // nodes
#define NE 320000    // edges
#define NR 500       // relations
#define EMBD 256
#define D4 64
#define BQ 32        // batch
#define TOT (2 * NN) // concatenated count length
#define NB 40        // scan blocks (40*1024 >= TOT)

#define NBLK_HIST 1250           // (NE+255)/256
#define NBLK_BN 448              // weight-pack blocks
#define NBLK_K1 (NBLK_HIST + NBLK_BN + 2 + BQ)

#define NBLK_GC1 939             // 313*3 C1-GEMM blocks
#define NBLK_GE1 32              // 8*4 E1-GEMM blocks
#define NBLK_MEGA (NBLK_GC1 + NBLK_GE1 + NBLK_HIST)

typedef __attribute__((ext_vector_type(8))) short bf16x8;
typedef __attribute__((ext_vector_type(4))) float f32x4;

__device__ __forceinline__ unsigned short f2bf(float x)
{
    unsigned int u = __float_as_uint(x);
    unsigned int r = (u + 0x7fffu + ((u >> 16) & 1u)) >> 16;   // RNE
    return (unsigned short)r;
}

__device__ __forceinline__ float4 bf4tof4(uint2 u)
{
    float4 r;
    r.x = __uint_as_float((u.x & 0xFFFFu) << 16);
    r.y = __uint_as_float(u.x & 0xFFFF0000u);
    r.z = __uint_as_float((u.y & 0xFFFFu) << 16);
    r.w = __uint_as_float(u.y & 0xFFFF0000u);
    return r;
}

// ---------------- K1: hist(+rank capture) | weight pack | params | rels-MLP ----------------
__global__ __launch_bounds__(256) void k_prep(
    const int* __restrict__ src, const int* __restrict__ dst,
    const int* __restrict__ evid, int* __restrict__ cnt, unsigned* __restrict__ rank2,
    const float* __restrict__ W_O1, const float* __restrict__ W_I1,
    const float* __restrict__ W_S1, const float* __restrict__ Wr1,
    const float* __restrict__ W_O2, const float* __restrict__ W_I2,
    const float* __restrict__ W_S2,
    unsigned short* __restrict__ Bn1, unsigned short* __restrict__ Bn2,
    const float* __restrict__ bO1, const float* __restrict__ bI1,
    const float* __restrict__ bS1,
    const float* __restrict__ g1, const float* __restrict__ bb1,
    const float* __restrict__ m1, const float* __restrict__ v1,
    const float* __restrict__ bO2, const float* __restrict__ bI2,
    const float* __restrict__ bS2,
    const float* __restrict__ g2, const float* __restrict__ bb2,
    const float* __restrict__ m2, const float* __restrict__ v2,
    float* __restrict__ s1, float* __restrict__ t1,
    float* __restrict__ s2, float* __restrict__ t2,
    const float* __restrict__ edge_embs,
    const float* __restrict__ br1, const float* __restrict__ br2,
    const float* __restrict__ Wr2full, const int* __restrict__ rids,
    float* __restrict__ rels)
{
    int b = blockIdx.x;
    if (b < NBLK_HIST) {
        int i = b * 256 + threadIdx.x;
        if (i < NE) {
            int r_in = atomicAdd(&cnt[dst[i]], 1);
            int r_out = atomicAdd(&cnt[NN + src[i]], 1);
            rank2[i] = (unsigned)r_in | ((unsigned)r_out << 16);
        }
        return;
    }
    b -= NBLK_HIST;
    if (b < NBLK_BN) {
        int id = b * 256 + threadIdx.x;
        if (id < 256 * 256) {
            int n = id >> 8, k = id & 255;
            float v;
            if (n < 64)       v = W_O1[n * 256 + k];
            else if (n < 128) v = W_I1[(n - 64) * 256 + k];
            else if (n < 192) v = W_S1[(n - 128) * 256 + k];
            else              v = Wr1[(n - 192) * 256 + k];
            Bn1[id] = f2bf(v);
        } else {
            int id2 = id - 256 * 256;
            if (id2 < 256 * 192) {
                int n = id2 / 192, k = id2 - n * 192;
                float v;
                if (k < 64)       v = W_O2[n * 64 + k];
                else if (k < 128) v = W_I2[n * 64 + (k - 64)];
                else              v = W_S2[n * 64 + (k - 128)];
                Bn2[id2] = f2bf(v);
            }
        }
        return;
    }
    b -= NBLK_BN;
    if (b < 2) {
        int i = b * 256 + threadIdx.x;   // [0,512)
        if (i < 64) {
            float rsg = g1[i] / sqrtf(v1[i] + 1e-5f);
            s1[i] = rsg * (1.f / 3.f);
            t1[i] = ((bO1[i] + bI1[i] + bS1[i]) * (1.f / 3.f) - m1[i]) * rsg + bb1[i];
        } else if (i < 320) {
            int n = i - 64;
            float rsg = g2[n] / sqrtf(v2[n] + 1e-5f);
            s2[n] = rsg * (1.f / 3.f);
            t2[n] = ((bO2[n] + bI2[n] + bS2[n]) * (1.f / 3.f) - m2[n]) * rsg + bb2[n];
        }
        return;
    }
    // rels MLP: rels[rb] = relu(edge_embs[rids[rb]] @ Wr1^T + br1) @ Wr2^T + br2
    {
        __shared__ float e_s[256];
        __shared__ float m_s[64];
        int rb = b - 2, o = threadIdx.x;
        int rid = rids[rb];
        e_s[o] = edge_embs[(size_t)rid * 256 + o];
        __syncthreads();
        if (o < 64) {
            float acc = br1[o];
            for (int k = 0; k < 256; ++k) acc = fmaf(e_s[k], Wr1[o * 256 + k], acc);
            m_s[o] = fmaxf(acc, 0.f);
        }
        __syncthreads();
        float r = br2[o];
        for (int jj = 0; jj < 64; ++jj) r = fmaf(m_s[jj], Wr2full[o * 64 + jj], r);
        rels[rb * 256 + o] = r;
    }
}

// ---------------- scan pipeline ----------------

__global__ __launch_bounds__(256) void k_scanA(const int* __restrict__ cnt,
                                               int* __restrict__ bsum)
{
    __shared__ int lds[256];
    int t = threadIdx.x;
    int base = blockIdx.x * 1024 + t * 4;
    int s = 0;
    if (base + 3 < TOT) {
        int4 v = *(const int4*)(cnt + base);
        s = v.x + v.y + v.z + v.w;
    } else {
        for (int c = 0; c < 4; ++c) { int i = base + c; if (i < TOT) s += cnt[i]; }
    }
    lds[t] = s;
    __syncthreads();
    for (int d = 128; d > 0; d >>= 1) {
        if (t < d) lds[t] += lds[t + d];
        __syncthreads();
    }
    if (t == 0) bsum[blockIdx.x] = lds[0];
}

__global__ __launch_bounds__(64) void k_scanB(int* __restrict__ bsum)
{
    int t = threadIdx.x;
    int v = (t < NB) ? bsum[t] : 0;
#pragma unroll
    for (int d = 1; d < 64; d <<= 1) {
        int u = __shfl_up(v, d, 64);
        if (t >= d) v += u;
    }
    int ex = __shfl_up(v, 1, 64);
    if (t == 0) ex = 0;
    if (t < NB) bsum[t] = ex;
}

__global__ __launch_bounds__(256) void k_scanC(const int* __restrict__ cnt,
                                               const int* __restrict__ bsum,
                                               int* __restrict__ offc)
{
    __shared__ int lds[256];
    int t = threadIdx.x;
    int base = blockIdx.x * 1024 + t * 4;
    int e0 = 0, e1 = 0, e2 = 0, e3 = 0;
    if (base + 3 < TOT) {
        int4 v = *(const int4*)(cnt + base);
        e0 = v.x; e1 = v.y; e2 = v.z; e3 = v.w;
    } else {
        if (base + 0 < TOT) e0 = cnt[base + 0];
        if (base + 1 < TOT) e1 = cnt[base + 1];
        if (base + 2 < TOT) e2 = cnt[base + 2];
        if (base + 3 < TOT) e3 = cnt[base + 3];
    }
    int s = e0 + e1 + e2 + e3;
    lds[t] = s;
    __syncthreads();
    for (int d = 1; d < 256; d <<= 1) {
        int u = (t >= d) ? lds[t - d] : 0;
        __syncthreads();
        lds[t] += u;
        __syncthreads();
    }
    int run = lds[t] - s + bsum[blockIdx.x];
    if (base + 3 < TOT) {
        int4 o = make_int4(run, run + e0, run + e0 + e1, run + e0 + e1 + e2);
        *(int4*)(offc + base) = o;
    } else {
        int r = run;
        if (base + 0 < TOT) { offc[base + 0] = r; r += e0; }
        if (base + 1 < TOT) { offc[base + 1] = r; r += e1; }
        if (base + 2 < TOT) { offc[base + 2] = r; r += e2; }
        if (base + 3 < TOT) { offc[base + 3] = r; r += e3; }
    }
    if (blockIdx.x == 0 && t == 0) offc[TOT] = 2 * NE;
}

// ---------------- MFMA bf16 GEMM body (device fn) ----------------
// aBf16: A is bf16 [M][lda] (lda in elems); else f32 converted in staging.
// mode 0: bf16 raw store (C=ushort*, ldc). mode 1: E1b epilogue (tanh(v+sv[gn-192]) bf16).
// mode 2: f32 hn epilogue tanh(acc*sv+tv) / node_embs passthrough.
__device__ __forceinline__ void gemm_dev(
    unsigned short* As, unsigned short* Bs,
    const void* __restrict__ Av, int aBf16, int M, int K, int lda,
    const unsigned short* __restrict__ Bn,
    void* __restrict__ C, int ldc, int mode,
    const float* __restrict__ sv, const float* __restrict__ tv,
    const float* __restrict__ node_embs, const int* __restrict__ flag,
    int m0, int n0)
{
    const int t = threadIdx.x;
    const int lane = t & 63, wave = t >> 6;
    const int wr = wave >> 1, wc = wave & 1;
    const int lrow = lane & 15, lkg = lane >> 4;

    f32x4 acc[2][2] = {};

    for (int kb = 0; kb < K; kb += 64) {
        if (aBf16) {
            const unsigned short* A = (const unsigned short*)Av;
#pragma unroll
            for (int it = 0; it < 2; ++it) {
                int idx = t + it * 256;
                int ko = idx & 7;
                int row = idx >> 3;
                int gm = m0 + row;
                uint4 a = make_uint4(0u, 0u, 0u, 0u);
                if (gm < M) a = *(const uint4*)(A + (size_t)gm * lda + kb + 8 * ko);
                *(uint4*)&As[row * 72 + 8 * ko] = a;
            }
        } else {
            const float* A = (const float*)Av;
#pragma unroll
            for (int it = 0; it < 4; ++it) {
                int idx = t + it * 256;
                int kq = idx & 15;
                int row = idx >> 4;
                int gm = m0 + row;
                float4 a = make_float4(0.f, 0.f, 0.f, 0.f);
                if (gm < M) a = *(const float4*)(A + (size_t)gm * lda + kb + 4 * kq);
                unsigned int p0 = (unsigned int)f2bf(a.x) | ((unsigned int)f2bf(a.y) << 16);
                unsigned int p1 = (unsigned int)f2bf(a.z) | ((unsigned int)f2bf(a.w) << 16);
                *(uint2*)&As[row * 72 + 4 * kq] = make_uint2(p0, p1);
            }
        }
#pragma unroll
        for (int it = 0; it < 2; ++it) {
            int idx = t + it * 256;
            int ko = idx & 7;
            int row = idx >> 3;
            uint4 b = *(const uint4*)(Bn + (size_t)(n0 + row) * K + kb + 8 * ko);
            *(uint4*)&Bs[row * 72 + 8 * ko] = b;
        }
        __syncthreads();
#pragma unroll
        for (int ks = 0; ks < 2; ++ks) {
            int k0 = ks * 32 + lkg * 8;
            bf16x8 af0 = *(const bf16x8*)&As[(wr * 32 + lrow) * 72 + k0];
            bf16x8 af1 = *(const bf16x8*)&As[(wr * 32 + 16 + lrow) * 72 + k0];
            bf16x8 bf0 = *(const bf16x8*)&Bs[(wc * 32 + lrow) * 72 + k0];
            bf16x8 bf1 = *(const bf16x8*)&Bs[(wc * 32 + 16 + lrow) * 72 + k0];
            acc[0][0] = __builtin_amdgcn_mfma_f32_16x16x32_bf16(af0, bf0, acc[0][0], 0, 0, 0);
            acc[0][1] = __builtin_amdgcn_mfma_f32_16x16x32_bf16(af0, bf1, acc[0][1], 0, 0, 0);
            acc[1][0] = __builtin_amdgcn_mfma_f32_16x16x32_bf16(af1, bf0, acc[1][0], 0, 0, 0);
            acc[1][1] = __builtin_amdgcn_mfma_f32_16x16x32_bf16(af1, bf1, acc[1][1], 0, 0, 0);
        }
        __syncthreads();
    }

#pragma unroll
    for (int m = 0; m < 2; ++m) {
#pragma unroll
        for (int r = 0; r < 4; ++r) {
            int gm = m0 + wr * 32 + m * 16 + lkg * 4 + r;
            if (gm >= M) continue;
#pragma unroll
            for (int n = 0; n < 2; ++n) {
                int gn = n0 + wc * 32 + n * 16 + lrow;
                float v = acc[m][n][r];
                if (mode == 0) {
                    ((unsigned short*)C)[(size_t)gm * ldc + gn] = f2bf(v);
                } else if (mode == 1) {
                    float val = (gn >= 192) ? tanhf(v + sv[gn - 192]) : v;
                    ((unsigned short*)C)[(size_t)gm * ldc + gn] = f2bf(val);
                } else {
                    float val = tanhf(v * sv[gn] + tv[gn]);
                    if (flag[0] == 0) val = node_embs[(size_t)gm * EMBD + gn];
                    ((float*)C)[(size_t)gm * EMBD + gn] = val;
                }
            }
        }
    }
}

// standalone GEMM kernel (final hn GEMM)
__global__ __launch_bounds__(256) void gemm_mfma(
    const void* __restrict__ A, int aBf16, int M, int K, int lda,
    const unsigned short* __restrict__ Bn,
    void* __restrict__ C, int ldc, int mode,
    const float* __restrict__ sv, const float* __restrict__ tv,
    const float* __restrict__ node_embs, const int* __restrict__ flag)
{
    __shared__ unsigned short As[64 * 72];
    __shared__ unsigned short Bs[64 * 72];
    gemm_dev(As, Bs, A, aBf16, M, K, lda, Bn, C, ldc, mode, sv, tv, node_embs, flag,
             blockIdx.x * 64, blockIdx.y * 64);
}

// ---------------- K5: scatter (atomic-free) || C1-GEMM || E1-GEMM ----------------
__global__ __launch_bounds__(256) void k_mega(
    const float* __restrict__ node_embs, const float* __restrict__ edge_embs,
    const unsigned short* __restrict__ Bn1,
    unsigned short* __restrict__ C1b, unsigned short* __restrict__ E1b,
    const float* __restrict__ br1,
    const int* __restrict__ src, const int* __restrict__ dst,
    const int* __restrict__ evid, const unsigned* __restrict__ rank2,
    const int* __restrict__ offc, unsigned* __restrict__ R)
{
    __shared__ unsigned short As[64 * 72];
    __shared__ unsigned short Bs[64 * 72];
    int bid = blockIdx.x;
    if (bid < NBLK_GC1) {
        // C1b = bf16( node_embs @ Bn1[0:192]^T )
        gemm_dev(As, Bs, node_embs, 0, NN, 256, 256, Bn1, C1b, 192, 0,
                 nullptr, nullptr, nullptr, nullptr,
                 (bid % 313) * 64, (bid / 313) * 64);
    } else if (bid < NBLK_GC1 + NBLK_GE1) {
        // E1b = bf16( edge_embs @ Bn1^T ), fused er1 tanh on cols [192,256)
        int b2 = bid - NBLK_GC1;
        gemm_dev(As, Bs, edge_embs, 0, NR, 256, 256, Bn1, E1b, 256, 1,
                 br1, nullptr, nullptr, nullptr,
                 (b2 % 8) * 64, (b2 / 8) * 64);
    } else {
        int e = (bid - NBLK_GC1 - NBLK_GE1) * 256 + threadIdx.x;
        if (e < NE) {
            int s = src[e], d = dst[e];
            unsigned rv = (unsigned)evid[e] << 15;
            unsigned rk = rank2[e];
            R[offc[d] + (rk & 0xFFFFu)] = (unsigned)s | rv;
            R[offc[NN + s] + (rk >> 16)] = (unsigned)d | rv;
        }
    }
}

// ---------------- CSR gather, quad-group bf16 rows ----------------

__device__ __forceinline__ void gather_quad(
    const unsigned* __restrict__ R, int r0, int r1, int g, int q,
    const unsigned short* __restrict__ TAB, int ldt, int toff,
    const unsigned short* __restrict__ ETAB, int eoff,
    float4& acc)
{
    int lane = g * 16 + q;
    int cnt = r1 - r0;
    for (int base = 0; base < cnt; base += 64) {
        int rem = cnt - base; if (rem > 64) rem = 64;
        unsigned rec = 0u;
        if (lane < rem) rec = R[r0 + base + lane];
        int i = 0;
        for (; 4 * i + 15 < rem; i += 4) {
            unsigned ra = __shfl(rec, 4 * i + g, 64);
            unsigned rb = __shfl(rec, 4 * i + 4 + g, 64);
            unsigned rc = __shfl(rec, 4 * i + 8 + g, 64);
            unsigned rd = __shfl(rec, 4 * i + 12 + g, 64);
            uint2 ua0 = *(const uint2*)(TAB + (size_t)(ra & 0x7FFFu) * ldt + toff + 4 * q);
            uint2 ue0 = *(const uint2*)(ETAB + (size_t)(ra >> 15) * 256 + eoff + 4 * q);
            uint2 ua1 = *(const uint2*)(TAB + (size_t)(rb & 0x7FFFu) * ldt + toff + 4 * q);
            uint2 ue1 = *(const uint2*)(ETAB + (size_t)(rb >> 15) * 256 + eoff + 4 * q);
            uint2 ua2 = *(const uint2*)(TAB + (size_t)(rc & 0x7FFFu) * ldt + toff + 4 * q);
            uint2 ue2 = *(const uint2*)(ETAB + (size_t)(rc >> 15) * 256 + eoff + 4 * q);
            uint2 ua3 = *(const uint2*)(TAB + (size_t)(rd & 0x7FFFu) * ldt + toff + 4 * q);
            uint2 ue3 = *(const uint2*)(ETAB + (size_t)(rd >> 15) * 256 + eoff + 4 * q);
            float4 a0 = bf4tof4(ua0), e0 = bf4tof4(ue0);
            float4 a1 = bf4tof4(ua1), e1 = bf4tof4(ue1);
            float4 a2 = bf4tof4(ua2), e2 = bf4tof4(ue2);
            float4 a3 = bf4tof4(ua3), e3 = bf4tof4(ue3);
            acc.x += (a0.x - e0.x) + (a1.x - e1.x) + (a2.x - e2.x) + (a3.x - e3.x);
            acc.y += (a0.y - e0.y) + (a1.y - e1.y) + (a2.y - e2.y) + (a3.y - e3.y);
            acc.z += (a0.z - e0.z) + (a1.z - e1.z) + (a2.z - e2.z) + (a3.z - e3.z);
            acc.w += (a0.w - e0.w) + (a1.w - e1.w) + (a2.w - e2.w) + (a3.w - e3.w);
        }
        for (; 4 * i < rem; ++i) {
            int idx = 4 * i + g;
            unsigned rr = __shfl(rec, idx < rem ? idx : 0, 64);
            if (idx < rem) {
                uint2 ua = *(const uint2*)(TAB + (size_t)(rr & 0x7FFFu) * ldt + toff + 4 * q);
                uint2 ue = *(const uint2*)(ETAB + (size_t)(rr >> 15) * 256 + eoff + 4 * q);
                float4 a = bf4tof4(ua), e = bf4tof4(ue);
                acc.x += a.x - e.x; acc.y += a.y - e.y;
                acc.z += a.z - e.z; acc.w += a.w - e.w;
            }
        }
    }
}

__device__ __forceinline__ void xreduce(float4& v)
{
    v.x += __shfl_xor(v.x, 16, 64); v.y += __shfl_xor(v.y, 16, 64);
    v.z += __shfl_xor(v.z, 16, 64); v.w += __shfl_xor(v.w, 16, 64);
    v.x += __shfl_xor(v.x, 32, 64); v.y += __shfl_xor(v.y, 32, 64);
    v.z += __shfl_xor(v.z, 32, 64); v.w += __shfl_xor(v.w, 32, 64);
}

__device__ __forceinline__ uint2 packbf4(float4 o)
{
    return make_uint2((unsigned)f2bf(o.x) | ((unsigned)f2bf(o.y) << 16),
                      (unsigned)f2bf(o.z) | ((unsigned)f2bf(o.w) << 16));
}

// layer 1 fused with combine: h1 = tanh((accO/deg_in + accI/deg_out + hS1raw)*s1 + t1) -> A2b[.,128:192) bf16
__global__ __launch_bounds__(256) void k_gather1(
    const int* __restrict__ offc, const unsigned* __restrict__ R,
    const unsigned short* __restrict__ C1b, const unsigned short* __restrict__ E1b,
    const float* __restrict__ s1, const float* __restrict__ t1,
    unsigned short* __restrict__ A2b)
{
    int n = blockIdx.x * 4 + (threadIdx.x >> 6);
    if (n >= NN) return;
    int lane = threadIdx.x & 63, g = lane >> 4, q = lane & 15;
    int b0 = offc[n], b1 = offc[n + 1];
    int c0 = offc[NN + n], c1 = offc[NN + n + 1];
    float di = 1.f / fmaxf((float)(b1 - b0), 1.f);
    float dh = 1.f / fmaxf((float)(c1 - c0), 1.f);
    float4 accO = make_float4(0.f, 0.f, 0.f, 0.f);
    float4 accI = make_float4(0.f, 0.f, 0.f, 0.f);
    gather_quad(R, b0, b1, g, q, C1b, 192, 0, E1b, 0, accO);
    gather_quad(R, c0, c1, g, q, C1b, 192, 64, E1b, 64, accI);
    xreduce(accO);
    xreduce(accI);
    if (g == 0) {
        float4 hs = bf4tof4(*(const uint2*)(C1b + (size_t)n * 192 + 128 + 4 * q));
        float4 sv = *(const float4*)(s1 + 4 * q);
        float4 tv = *(const float4*)(t1 + 4 * q);
        float4 o;
        o.x = tanhf((accO.x * di + accI.x * dh + hs.x) * sv.x + tv.x);
        o.y = tanhf((accO.y * di + accI.y * dh + hs.y) * sv.y + tv.y);
        o.z = tanhf((accO.z * di + accI.z * dh + hs.z) * sv.z + tv.z);
        o.w = tanhf((accO.w * di + accI.w * dh + hs.w) * sv.w + tv.w);
        *(uint2*)(A2b + (size_t)n * 192 + 128 + 4 * q) = packbf4(o);
    }
}

// layer 2: both dirs read h1 (A2b cols[128,192)) minus er1 (E1b cols[192,256)) -> A2b cols [0,128)
__global__ __launch_bounds__(256) void k_gather2(
    const int* __restrict__ offc, const unsigned* __restrict__ R,
    const unsigned short* __restrict__ A2r, const unsigned short* __restrict__ E1b,
    unsigned short* __restrict__ A2w)
{
    int n = blockIdx.x * 4 + (threadIdx.x >> 6);
    if (n >= NN) return;
    int lane = threadIdx.x & 63, g = lane >> 4, q = lane & 15;
    int b0 = offc[n], b1 = offc[n + 1];
    int c0 = offc[NN + n], c1 = offc[NN + n + 1];
    float di = 1.f / fmaxf((float)(b1 - b0), 1.f);
    float dh = 1.f / fmaxf((float)(c1 - c0), 1.f);
    float4 accO = make_float4(0.f, 0.f, 0.f, 0.f);
    float4 accI = make_float4(0.f, 0.f, 0.f, 0.f);
    gather_quad(R, b0, b1, g, q, A2r, 192, 128, E1b, 192, accO);
    gather_quad(R, c0, c1, g, q, A2r, 192, 128, E1b, 192, accI);
    xreduce(accO);
    xreduce(accI);
    if (g == 0) {
        float4 o0, o1;
        o0.x = accO.x * di; o0.y = accO.y * di; o0.z = accO.z * di; o0.w = accO.w * di;
        o1.x = accI.x * dh; o1.y = accI.y * dh; o1.z = accI.z * dh; o1.w = accI.w * dh;
        *(uint2*)(A2w + (size_t)n * 192 + 4 * q) = packbf4(o0);
        *(uint2*)(A2w + (size_t)n * 192 + 64 + 4 * q) = packbf4(o1);
    }
}

// ---------------- scoring ----------------
__global__ __launch_bounds__(256) void k_tvec(
    const float* __restrict__ rels, const float* __restrict__ hn,
    const int* __restrict__ hids, const int* __restrict__ tids,
    const int* __restrict__ is_head, float* __restrict__ tvec)
{
    int b = blockIdx.x, o = threadIdx.x;
    int ih = is_head[0];
    int nid = ih ? tids[b] : hids[b];
    float r = rels[b * 256 + o];
    float hv = hn[(size_t)nid * 256 + o];
    tvec[b * 256 + o] = ih ? (hv - r) : (hv + r);
}

__global__ __launch_bounds__(256) void k_score(
    const float* __restrict__ hn, const float* __restrict__ tvec,
    float* __restrict__ score)
{
    int p = blockIdx.x * 4 + (threadIdx.x >> 6);
    if (p >= BQ * (NN / BQ)) return;
    int l = threadIdx.x & 63;
    int b = p / (NN / BQ);
    int j = p - b * (NN / BQ);
    int idx = (b * NN + 32 * j) / BQ;   // faithful repeat_interleave indexing
    float ssum = 0.f;
#pragma unroll
    for (int q = 0; q < 4; ++q) {
        float df = hn[(size_t)idx * 256 + l + 64 * q] - tvec[b * 256 + l + 64 * q];
        ssum = fmaf(df, df, ssum);
    }
#pragma unroll
    for (int off = 32; off >= 1; off >>= 1) ssum += __shfl_xor(ssum, off, 64);
    float dist = sqrtf(ssum);
    float sc = 1.f / (1.f + expf(dist - 12.f));
    if (l < 32) score[(size_t)b * NN + 32 * j + l] = sc;
}

// ---------------- launch ----------------
extern "C" void kernel_launch(void* const* d_in, const int* in_sizes, int n_in,
                              void* d_out, int out_size, void* d_ws, size_t ws_size,
                              hipStream_t stream)
{
    const float* node_embs = (const float*)d_in[0];
    const float* edge_embs = (const float*)d_in[1];
    const float* W_O1 = (const float*)d_in[2];  const float* b_O1 = (const float*)d_in[3];
    const float* W_I1 = (const float*)d_in[4];  const float* b_I1 = (const float*)d_in[5];
    const float* W_S1 = (const float*)d_in[6];  const float* b_S1 = (const float*)d_in[7];
    const float* bn1_g = (const float*)d_in[8]; const float* bn1_b = (const float*)d_in[9];
    const float* bn1_m = (const float*)d_in[10];const float* bn1_v = (const float*)d_in[11];
    const float* Wr1 = (const float*)d_in[12];  const float* br1 = (const float*)d_in[13];
    const float* W_O2 = (const float*)d_in[14]; const float* b_O2 = (const float*)d_in[15];
    const float* W_I2 = (const float*)d_in[16]; const float* b_I2 = (const float*)d_in[17];
    const float* W_S2 = (const float*)d_in[18]; const float* b_S2 = (const float*)d_in[19];
    const float* bn2_g = (const float*)d_in[20];const float* bn2_b = (const float*)d_in[21];
    const float* bn2_m = (const float*)d_in[22];const float* bn2_v = (const float*)d_in[23];
    const float* Wr2 = (const float*)d_in[24];  const float* br2 = (const float*)d_in[25];
    const int* src = (const int*)d_in[26];
    const int* dst = (const int*)d_in[27];
    const int* evid = (const int*)d_in[28];
    const int* hids = (const int*)d_in[29];
    const int* rids = (const int*)d_in[30];
    const int* tids = (const int*)d_in[31];
    const int* upd = (const int*)d_in[32];
    const int* ihead = (const int*)d_in[33];

    // bf16 tables first (all sizes multiple of 8 ushorts -> 16B aligned)
    unsigned short* C1b = (unsigned short*)d_ws;           // 20000*192
    unsigned short* A2b = C1b + 3840000;                   // 20000*192
    unsigned short* E1b = A2b + 3840000;                   // 500*256
    unsigned short* Bn1 = E1b + 128000;                    // 256*256
    unsigned short* Bn2 = Bn1 + 65536;                     // 256*192

    float* s1   = (float*)(Bn2 + 49152);   // 64
    float* t1   = s1 + 64;                 // 64
    float* s2   = t1 + 64;                 // 256
    float* t2   = s2 + 256;                // 256
    float* rels = t2 + 256;                // 32*256
    float* tvec = rels + 8192;             // 32*256

    unsigned* R     = (unsigned*)(tvec + 8192);  // 2*NE packed records
    unsigned* rank2 = R + 2 * NE;                // NE (rank_in | rank_out<<16)
    int* cnt    = (int*)(rank2 + NE);      // TOT
    int* offc   = cnt + TOT;               // TOT+1
    int* bsum   = offc + TOT + 1;          // NB

    float* hn    = (float*)d_out;                       // 20000*256
    float* score = hn + (size_t)NN * EMBD;              // 32*20000

    hipMemsetAsync(cnt, 0, (size_t)TOT * 4, stream);

    // K1: hist(+ranks) || weight-pack || params || rels-MLP
    k_prep<<<NBLK_K1, 256, 0, stream>>>(
        src, dst, evid, cnt, rank2,
        W_O1, W_I1, W_S1, Wr1, W_O2, W_I2, W_S2, Bn1, Bn2,
        b_O1, b_I1, b_S1, bn1_g, bn1_b, bn1_m, bn1_v,
        b_O2, b_I2, b_S2, bn2_g, bn2_b, bn2_m, bn2_v,
        s1, t1, s2, t2,
        edge_embs, br1, br2, Wr2, rids, rels);

    // scan pipeline
    k_scanA<<<NB, 256, 0, stream>>>(cnt, bsum);
    k_scanB<<<1, 64, 0, stream>>>(bsum);
    k_scanC<<<NB, 256, 0, stream>>>(cnt, bsum, offc);

    // K5: scatter (atomic-free) || C1-GEMM || E1-GEMM
    k_mega<<<NBLK_MEGA, 256, 0, stream>>>(node_embs, edge_embs, Bn1,
                                          C1b, E1b, br1, src, dst, evid, rank2, offc, R);

    // layer-1 aggregation + combine (writes h1 into A2b cols [128,192))
    k_gather1<<<NN / 4, 256, 0, stream>>>(offc, R, C1b, E1b, s1, t1, A2b);
    // layer-2 aggregation (writes A2b cols [0,128))
    k_gather2<<<NN / 4, 256, 0, stream>>>(offc, R, A2b, E1b, A2b);

    // hn = tanh((A2b @ Bn2^T) * s2 + t2)  (or node_embs if !upd)  (M=20000, K=192, A bf16)
    gemm_mfma<<<dim3(313, 4), 256, 0, stream>>>(A2b, 1, NN, 192, 192, Bn2,
                                                hn, 256, 2, s2, t2, node_embs, upd);

    k_tvec<<<BQ, 256, 0, stream>>>(rels, hn, hids, tids, ihead, tvec);
    k_score<<<(BQ * (NN / BQ)) / 4, 256, 0, stream>>>(hn, tvec, score);
}